// Round 2
// baseline (812.617 us; speedup 1.0000x reference)
//
#include <hip/hip_runtime.h>
#include <hip/hip_fp16.h>

// ---- problem constants ----
#define SQ   1024
#define DM   1024
#define NH   16
#define HD   64
#define BSZ  4

typedef _Float16 f16;
typedef f16  f16x8 __attribute__((ext_vector_type(8)));
typedef f16  f16x4 __attribute__((ext_vector_type(4)));
typedef float f32x4 __attribute__((ext_vector_type(4)));

#define MFMA16(a,b,c) __builtin_amdgcn_mfma_f32_16x16x32_f16(a,b,c,0,0,0)

// async global->LDS, 16B per lane (dest = wave-uniform base + lane*16; no padding!)
#define GLOAD_LDS(g, l) __builtin_amdgcn_global_load_lds( \
    (const __attribute__((address_space(1))) void*)(g), \
    (__attribute__((address_space(3))) void*)(l), 16, 0, 0)

// ws layout in halves:
//  [0)            xin16: query,key,value fp16   3 * 4194304
//  [12582912)     w16:   Wq,Wk,Wv fp16          3 * 1048576
//  [15728640)     er16:  Er fp16                16*2049*64 = 2098176
//  [17826816)     qkv16: q,k,v fp16 [b,h,s,64]  3 * 4194304
//  [30409728)     vt16:  v^T fp16 [b,h,64,s]    4194304
#define XIN16OFF  0
#define W16OFF    12582912
#define ER16OFF   15728640
#define QKV16OFF  17826816
#define VTOFF     30409728

// ---------------- kernel 1: fp32 -> fp16 conversion ----------------
__global__ __launch_bounds__(256) void cvt_all(
    const float* __restrict__ q, const float* __restrict__ k, const float* __restrict__ v,
    const float* __restrict__ wq, const float* __restrict__ wk, const float* __restrict__ wv,
    const float* __restrict__ er, f16* __restrict__ ws)
{
    int z = blockIdx.z;
    const float* src; f16* dst; int n;
    if (z < 3)      { src = (z==0)?q:((z==1)?k:v);    dst = ws + (size_t)z*4194304;              n = 4194304; }
    else if (z < 6) { src = (z==3)?wq:((z==4)?wk:wv); dst = ws + W16OFF + (size_t)(z-3)*1048576; n = 1048576; }
    else            { src = er;                        dst = ws + ER16OFF;                        n = 2098176; }
    int idx = (blockIdx.x*256 + threadIdx.x) * 8;
    if (idx >= n) return;
    float4 a = *(const float4*)&src[idx];
    float4 b = *(const float4*)&src[idx+4];
    f16x8 o;
    o[0]=(f16)a.x; o[1]=(f16)a.y; o[2]=(f16)a.z; o[3]=(f16)a.w;
    o[4]=(f16)b.x; o[5]=(f16)b.y; o[6]=(f16)b.z; o[7]=(f16)b.w;
    *(f16x8*)&dst[idx] = o;
}

// ---------------- kernel 2: projection GEMMs  C = X @ W^T + b ----------------
// v3: BK=64 (half the barrier drains, 32 MFMA/iter), pre-swizzled global source
// so global_load_lds dest stays linear but ds_read_b128 at row-stride 128B is
// bank-conflict-optimal (rule: linear dest + XOR'd source + XOR'd read).
// XCD-chunked bijective block swizzle (256 blocks per z, 32 per XCD).
__global__ __launch_bounds__(256) void proj_gemm(
    f16* __restrict__ ws, const float* __restrict__ bq,
    const float* __restrict__ bk, const float* __restrict__ bv)
{
    int z = blockIdx.z;
    const f16* X = ws + XIN16OFF + (size_t)z*4194304;
    const f16* W = ws + W16OFF   + (size_t)z*1048576;
    const float* bias = (z==0)?bq:((z==1)?bk:bv);
    f16* dst = ws + QKV16OFF + (size_t)z*4194304;

    // XCD swizzle within this z: 256 blocks, 8 XCDs, 32-consecutive per XCD
    int flat = blockIdx.y * 8 + blockIdx.x;
    int f = ((flat & 7) << 5) + (flat >> 3);
    int n0 = (f & 7) * 128, m0 = (f >> 3) * 128;

    int tid = threadIdx.x, lane = tid & 63, w = tid >> 6;
    int wm = (w >> 1) * 64, wn = (w & 1) * 64;

    __shared__ f16 As[128*64];
    __shared__ f16 Bs[128*64];

    f32x4 acc[4][4];
    #pragma unroll
    for (int a=0;a<4;++a)
        #pragma unroll
        for (int b=0;b<4;++b) { acc[a][b][0]=0.f;acc[a][b][1]=0.f;acc[a][b][2]=0.f;acc[a][b][3]=0.f; }

    int srow = tid >> 3;                              // 0..31
    int sdst = (tid & 7) << 3;                        // linear dest col (halves)
    int ssrc = (((tid & 7) ^ ((tid >> 3) & 7)) << 3); // pre-swizzled source col

    int fr = lane & 15, fkh = (lane >> 4) << 3;       // fkh in {0,8,16,24} halves
    int ra0 = (fkh)      ^ ((fr & 7) << 3);           // swizzled read offsets
    int ra1 = (fkh + 32) ^ ((fr & 7) << 3);

    for (int k0 = 0; k0 < 1024; k0 += 64) {
        __syncthreads();
        #pragma unroll
        for (int u = 0; u < 4; ++u) {
            GLOAD_LDS(&X[(size_t)(m0+srow+32*u)*1024 + k0 + ssrc], &As[(srow+32*u)*64 + sdst]);
            GLOAD_LDS(&W[(size_t)(n0+srow+32*u)*1024 + k0 + ssrc], &Bs[(srow+32*u)*64 + sdst]);
        }
        __syncthreads();   // compiler drains vmcnt before s_barrier
        f16x8 a0[4], a1[4], b0[4], b1[4];
        #pragma unroll
        for (int a=0;a<4;++a) {
            a0[a] = *(const f16x8*)&As[(wm + a*16 + fr)*64 + ra0];
            a1[a] = *(const f16x8*)&As[(wm + a*16 + fr)*64 + ra1];
        }
        #pragma unroll
        for (int bb=0;bb<4;++bb) {
            b0[bb] = *(const f16x8*)&Bs[(wn + bb*16 + fr)*64 + ra0];
            b1[bb] = *(const f16x8*)&Bs[(wn + bb*16 + fr)*64 + ra1];
        }
        #pragma unroll
        for (int a=0;a<4;++a)
            #pragma unroll
            for (int bb=0;bb<4;++bb) {
                acc[a][bb] = MFMA16(a0[a], b0[bb], acc[a][bb]);
                acc[a][bb] = MFMA16(a1[a], b1[bb], acc[a][bb]);
            }
    }

    int coln = lane & 15, rq = (lane >> 4) << 2;
    #pragma unroll
    for (int tb = 0; tb < 4; ++tb) {
        int j = n0 + wn + tb*16 + coln;
        int hh = j >> 6, dd = j & 63;
        float bsv = bias[j];
        #pragma unroll
        for (int ta = 0; ta < 4; ++ta) {
            #pragma unroll
            for (int r = 0; r < 4; ++r) {
                int m = m0 + wm + ta*16 + rq + r;
                int bidx = m >> 10, s = m & 1023;
                dst[((size_t)(bidx*16 + hh)*1024 + s)*64 + dd] = (f16)(acc[ta][tb][r] + bsv);
            }
        }
    }
}

// ---------------- kernel 3: transpose v -> vT [bh][d][s] ----------------
__global__ __launch_bounds__(256) void transpose_v(f16* __restrict__ ws)
{
    const f16* v = ws + QKV16OFF + 2*4194304 + (size_t)blockIdx.y*65536;
    f16* o       = ws + VTOFF               + (size_t)blockIdx.y*65536;
    int s0 = blockIdx.x << 6;
    __shared__ f16 t[64][72];
    int tid = threadIdx.x;
    int r = tid >> 2, c = (tid & 3) << 4;
    f16x8 a = *(const f16x8*)&v[(size_t)(s0+r)*64 + c];
    f16x8 b = *(const f16x8*)&v[(size_t)(s0+r)*64 + c + 8];
    #pragma unroll
    for (int j = 0; j < 8; ++j) { t[r][c+j] = a[j]; t[r][c+8+j] = b[j]; }
    __syncthreads();
    int dr = tid >> 2, sc0 = (tid & 3) << 4;
    f16x8 o1, o2;
    #pragma unroll
    for (int j = 0; j < 8; ++j) { o1[j] = t[sc0+j][dr]; o2[j] = t[sc0+8+j][dr]; }
    *(f16x8*)&o[(size_t)dr*1024 + s0 + sc0]     = o1;
    *(f16x8*)&o[(size_t)dr*1024 + s0 + sc0 + 8] = o2;
}

// ---------------- kernel 4: fused scores + softmax + attn-write + PV ----------------
// grid (64 s-blocks of 16 rows, 64 bh). 4 waves, wave w owns t-cols [w*256,(w+1)*256).
// v3 (two-pass recompute): phase 1 computes ONLY rowsums (nothing stored);
// one barrier; phase 2 recomputes identical scores, scales by 1/rowsum, stores
// normalized attn straight from registers (4x64B segments per dword store,
// spread through the loop), and runs PV interleaved via a 1.25KB wave-private
// LDS transpose buffer (same-wave DS ordering: no barrier). Kills the 32KB P16
// buffer: LDS 34->16.7KB, launch_bounds(256,5) -> 5 blocks/CU, 20 waves/CU.
__global__ __launch_bounds__(256, 5) void attn_pv(
    const f16* __restrict__ ws, float* __restrict__ attn, float* __restrict__ out)
{
    const f16* qkv = ws + QKV16OFF;
    const f16* er  = ws + ER16OFF;
    int bh = blockIdx.y, h = bh & 15, b = bh >> 4;
    int s0 = blockIdx.x << 4;
    int tid = threadIdx.x, lane = tid & 63, w = tid >> 6;

    const f16* qb  = qkv + (size_t)bh * 65536;
    const f16* kb  = qkv + 4194304 + (size_t)bh * 65536;
    const f16* vtb = ws + VTOFF + (size_t)bh * 65536;
    const f16* E   = er + (size_t)h * 2049 * 64;

    // LDS pool 16KB: pstage[4][16][40] f16 (5120B, wave-private PV transpose
    // buffers) overlaid after the phase-2 barrier by Ored[4][16][64] f32.
    __shared__ __align__(16) float lds_pool[4096];
    __shared__ float red[16][4];
    f16* pstage = (f16*)lds_pool + w * 640;   // [16][40] halves

    int fr = lane & 15, fk = (lane >> 4) << 3;
    int hi = lane >> 4;
    f16x8 qf0 = *(const f16x8*)&qb[(s0+fr)*64 + fk];
    f16x8 qf1 = *(const f16x8*)&qb[(s0+fr)*64 + fk + 32];

    int tbase = w << 8;
    int l0 = 1008 + tbase - s0;

    // ================= phase 1: row sums only =================
    f16x8 kf0 = *(const f16x8*)&kb[(tbase+fr)*64 + fk];
    f16x8 kf1 = *(const f16x8*)&kb[(tbase+fr)*64 + fk + 32];
    f16x8 e0a = *(const f16x8*)&E[(size_t)(l0+fr)*64 + fk];
    f16x8 e0b = *(const f16x8*)&E[(size_t)(l0+fr)*64 + fk + 32];
    f16x8 e1a = *(const f16x8*)&E[(size_t)(l0+16+fr)*64 + fk];
    f16x8 e1b = *(const f16x8*)&E[(size_t)(l0+16+fr)*64 + fk + 32];

    float rs[4] = {0.f, 0.f, 0.f, 0.f};

    #pragma unroll
    for (int i = 0; i < 16; ++i) {
        f16x8 nk0, nk1, nea, neb;
        if (i < 15) {
            int t0n = tbase + ((i+1) << 4);
            nk0 = *(const f16x8*)&kb[(t0n+fr)*64 + fk];
            nk1 = *(const f16x8*)&kb[(t0n+fr)*64 + fk + 32];
            int ln = l0 + ((i+2) << 4);   // max row touched: 2047 < 2049
            nea = *(const f16x8*)&E[(size_t)(ln+fr)*64 + fk];
            neb = *(const f16x8*)&E[(size_t)(ln+fr)*64 + fk + 32];
        }

        f32x4 c = {0.f,0.f,0.f,0.f};
        c = MFMA16(qf0, kf0, c);
        c = MFMA16(qf1, kf1, c);
        f32x4 r0 = {0.f,0.f,0.f,0.f};
        f32x4 r1 = {0.f,0.f,0.f,0.f};
        r0 = MFMA16(qf0, e0a, r0); r0 = MFMA16(qf1, e0b, r0);
        r1 = MFMA16(qf0, e1a, r1); r1 = MFMA16(qf1, e1b, r1);

        #pragma unroll
        for (int r = 0; r < 4; ++r) {
            int shat = (hi << 2) + r;
            int jj = fr - shat + 15;               // [0,30]
            int addr = ((lane & 48) | (jj & 15)) << 2;
            float m = (fr >= 15 - shat) ? r0[r] : r1[r];
            float g = __int_as_float(__builtin_amdgcn_ds_bpermute(addr, __float_as_int(m)));
            rs[r] += __expf((c[r] + g) * 0.125f);  // scores bounded; no max shift
        }

        if (i < 15) { kf0 = nk0; kf1 = nk1; e0a = e1a; e0b = e1b; e1a = nea; e1b = neb; }
    }

    // ---- block-wide row-sum reduce ----
    #pragma unroll
    for (int r = 0; r < 4; ++r) {
        float s = rs[r];
        s += __shfl_xor(s, 1); s += __shfl_xor(s, 2);
        s += __shfl_xor(s, 4); s += __shfl_xor(s, 8);
        rs[r] = s;
    }
    if (fr == 0) {
        #pragma unroll
        for (int r = 0; r < 4; ++r) red[(hi<<2)+r][w] = rs[r];
    }
    __syncthreads();   // barrier 1: red complete

    float inv4[4];
    #pragma unroll
    for (int r = 0; r < 4; ++r) {
        int rw = (hi<<2)+r;
        inv4[r] = 1.f / (red[rw][0] + red[rw][1] + red[rw][2] + red[rw][3]);
    }

    // ================= phase 2: recompute + store attn + PV =================
    float* arow0 = attn + ((size_t)bh*1024 + s0 + (hi<<2))*1024 + tbase + fr;

    f32x4 oacc[4];
    #pragma unroll
    for (int nb=0;nb<4;++nb) { oacc[nb][0]=0.f;oacc[nb][1]=0.f;oacc[nb][2]=0.f;oacc[nb][3]=0.f; }
    f16x8 bcur[4], bnxt[4];
    #pragma unroll
    for (int nb = 0; nb < 4; ++nb)
        bcur[nb] = *(const f16x8*)&vtb[(size_t)((nb<<4)+fr)*1024 + tbase + fk];

    #pragma unroll
    for (int i = 0; i < 16; ++i) {
        // K/E reload — L1/L2-hot from phase 1; compiler hoists within unroll
        int t0 = tbase + (i << 4);
        f16x8 pk0 = *(const f16x8*)&kb[(t0+fr)*64 + fk];
        f16x8 pk1 = *(const f16x8*)&kb[(t0+fr)*64 + fk + 32];
        int la = l0 + (i << 4);
        f16x8 pea = *(const f16x8*)&E[(size_t)(la+fr)*64 + fk];
        f16x8 peb = *(const f16x8*)&E[(size_t)(la+fr)*64 + fk + 32];
        f16x8 pfa = *(const f16x8*)&E[(size_t)(la+16+fr)*64 + fk];
        f16x8 pfb = *(const f16x8*)&E[(size_t)(la+16+fr)*64 + fk + 32];

        f32x4 c = {0.f,0.f,0.f,0.f};
        c = MFMA16(qf0, pk0, c);
        c = MFMA16(qf1, pk1, c);
        f32x4 r0 = {0.f,0.f,0.f,0.f};
        f32x4 r1 = {0.f,0.f,0.f,0.f};
        r0 = MFMA16(qf0, pea, r0); r0 = MFMA16(qf1, peb, r0);
        r1 = MFMA16(qf0, pfa, r1); r1 = MFMA16(qf1, pfb, r1);

        #pragma unroll
        for (int r = 0; r < 4; ++r) {
            int shat = (hi << 2) + r;
            int jj = fr - shat + 15;
            int addr = ((lane & 48) | (jj & 15)) << 2;
            float m = (fr >= 15 - shat) ? r0[r] : r1[r];
            float g = __int_as_float(__builtin_amdgcn_ds_bpermute(addr, __float_as_int(m)));
            float en = __expf((c[r] + g) * 0.125f) * inv4[r];   // normalized
            arow0[(size_t)r*1024 + (i<<4)] = en;                // coalesced 4x64B
            pstage[shat*40 + ((i&1)<<4) + fr] = (f16)en;
        }

        if (i & 1) {
            const int kc = i >> 1;
            if (kc < 7) {
                #pragma unroll
                for (int nb = 0; nb < 4; ++nb)
                    bnxt[nb] = *(const f16x8*)&vtb[(size_t)((nb<<4)+fr)*1024 + tbase + ((kc+1)<<5) + fk];
            }
            f16x8 af = *(const f16x8*)&pstage[fr*40 + fk];   // same-wave DS order
            #pragma unroll
            for (int nb = 0; nb < 4; ++nb)
                oacc[nb] = MFMA16(af, bcur[nb], oacc[nb]);
            if (kc < 7) {
                #pragma unroll
                for (int nb = 0; nb < 4; ++nb) bcur[nb] = bnxt[nb];
            }
        }
    }

    __syncthreads();   // barrier 2: all waves done with pstage -> overlay Ored
    float* Ored = lds_pool;
    #pragma unroll
    for (int nb = 0; nb < 4; ++nb)
        #pragma unroll
        for (int r = 0; r < 4; ++r)
            Ored[w*1024 + ((hi<<2)+r)*64 + (nb<<4) + fr] = oacc[nb][r];  // already normalized
    __syncthreads();   // barrier 3
    {
        int frow = tid >> 4, fc = (tid & 15) << 2;
        float4 s4;
        s4.x = Ored[frow*64+fc+0] + Ored[1024+frow*64+fc+0] + Ored[2048+frow*64+fc+0] + Ored[3072+frow*64+fc+0];
        s4.y = Ored[frow*64+fc+1] + Ored[1024+frow*64+fc+1] + Ored[2048+frow*64+fc+1] + Ored[3072+frow*64+fc+1];
        s4.z = Ored[frow*64+fc+2] + Ored[1024+frow*64+fc+2] + Ored[2048+frow*64+fc+2] + Ored[3072+frow*64+fc+2];
        s4.w = Ored[frow*64+fc+3] + Ored[1024+frow*64+fc+3] + Ored[2048+frow*64+fc+3] + Ored[3072+frow*64+fc+3];
        *(float4*)&out[((size_t)b*1024 + s0 + frow)*1024 + h*64 + fc] = s4;
    }
}

extern "C" void kernel_launch(void* const* d_in, const int* in_sizes, int n_in,
                              void* d_out, int out_size, void* d_ws, size_t ws_size,
                              hipStream_t stream) {
    const float* query = (const float*)d_in[0];
    const float* key   = (const float*)d_in[1];
    const float* value = (const float*)d_in[2];
    const float* Wq    = (const float*)d_in[3];
    const float* bq    = (const float*)d_in[4];
    const float* Wk    = (const float*)d_in[5];
    const float* bk    = (const float*)d_in[6];
    const float* Wv    = (const float*)d_in[7];
    const float* bv    = (const float*)d_in[8];

    f16*   ws   = (f16*)d_ws;
    float* out  = (float*)d_out;            // 4,194,304 floats
    float* attn = out + 4194304;            // 67,108,864 floats

    cvt_all    <<<dim3(2048, 1, 7), 256, 0, stream>>>(query, key, value, Wq, Wk, Wv,
                                                      (const float*)d_in[9], ws);
    proj_gemm  <<<dim3(8, 32, 3),   256, 0, stream>>>(ws, bq, bk, bv);
    transpose_v<<<dim3(16, 64),     256, 0, stream>>>(ws);
    attn_pv    <<<dim3(64, 64),     256, 0, stream>>>(ws, attn, out);
}

// Round 4
// 533.782 us; speedup vs baseline: 1.5224x; 1.5224x over previous
//
#include <hip/hip_runtime.h>
#include <hip/hip_fp16.h>

// ---- problem constants ----
#define SQ   1024
#define DM   1024
#define NH   16
#define HD   64
#define BSZ  4

typedef _Float16 f16;
typedef f16  f16x8 __attribute__((ext_vector_type(8)));
typedef f16  f16x4 __attribute__((ext_vector_type(4)));
typedef float f32x4 __attribute__((ext_vector_type(4)));

#define MFMA16(a,b,c) __builtin_amdgcn_mfma_f32_16x16x32_f16(a,b,c,0,0,0)

// async global->LDS, 16B per lane (dest = wave-uniform base + lane*16; no padding!)
#define GLOAD_LDS(g, l) __builtin_amdgcn_global_load_lds( \
    (const __attribute__((address_space(1))) void*)(g), \
    (__attribute__((address_space(3))) void*)(l), 16, 0, 0)

// ws layout in halves:
//  [0)            xin16: query,key,value fp16   3 * 4194304
//  [12582912)     w16:   Wq,Wk,Wv fp16          3 * 1048576
//  [15728640)     er16:  Er fp16                16*2049*64 = 2098176
//  [17826816)     qkv16: q,k,v fp16 [b,h,s,64]  3 * 4194304
//  [30409728)     vt16:  v^T fp16 [b,h,64,s]    4194304
#define XIN16OFF  0
#define W16OFF    12582912
#define ER16OFF   15728640
#define QKV16OFF  17826816
#define VTOFF     30409728

// ---------------- kernel 1: fp32 -> fp16 conversion ----------------
__global__ __launch_bounds__(256) void cvt_all(
    const float* __restrict__ q, const float* __restrict__ k, const float* __restrict__ v,
    const float* __restrict__ wq, const float* __restrict__ wk, const float* __restrict__ wv,
    const float* __restrict__ er, f16* __restrict__ ws)
{
    int z = blockIdx.z;
    const float* src; f16* dst; int n;
    if (z < 3)      { src = (z==0)?q:((z==1)?k:v);    dst = ws + (size_t)z*4194304;              n = 4194304; }
    else if (z < 6) { src = (z==3)?wq:((z==4)?wk:wv); dst = ws + W16OFF + (size_t)(z-3)*1048576; n = 1048576; }
    else            { src = er;                        dst = ws + ER16OFF;                        n = 2098176; }
    int idx = (blockIdx.x*256 + threadIdx.x) * 8;
    if (idx >= n) return;
    float4 a = *(const float4*)&src[idx];
    float4 b = *(const float4*)&src[idx+4];
    f16x8 o;
    o[0]=(f16)a.x; o[1]=(f16)a.y; o[2]=(f16)a.z; o[3]=(f16)a.w;
    o[4]=(f16)b.x; o[5]=(f16)b.y; o[6]=(f16)b.z; o[7]=(f16)b.w;
    *(f16x8*)&dst[idx] = o;
}

// ---------------- kernel 2: projection GEMMs  C = X @ W^T + b ----------------
// v3: BK=64, pre-swizzled global source + XOR'd LDS read (linear gload_lds dest),
// XCD-chunked bijective block swizzle.
__global__ __launch_bounds__(256) void proj_gemm(
    f16* __restrict__ ws, const float* __restrict__ bq,
    const float* __restrict__ bk, const float* __restrict__ bv)
{
    int z = blockIdx.z;
    const f16* X = ws + XIN16OFF + (size_t)z*4194304;
    const f16* W = ws + W16OFF   + (size_t)z*1048576;
    const float* bias = (z==0)?bq:((z==1)?bk:bv);
    f16* dst = ws + QKV16OFF + (size_t)z*4194304;

    // XCD swizzle within this z: 256 blocks, 8 XCDs, 32-consecutive per XCD
    int flat = blockIdx.y * 8 + blockIdx.x;
    int f = ((flat & 7) << 5) + (flat >> 3);
    int n0 = (f & 7) * 128, m0 = (f >> 3) * 128;

    int tid = threadIdx.x, lane = tid & 63, w = tid >> 6;
    int wm = (w >> 1) * 64, wn = (w & 1) * 64;

    __shared__ f16 As[128*64];
    __shared__ f16 Bs[128*64];

    f32x4 acc[4][4];
    #pragma unroll
    for (int a=0;a<4;++a)
        #pragma unroll
        for (int b=0;b<4;++b) { acc[a][b][0]=0.f;acc[a][b][1]=0.f;acc[a][b][2]=0.f;acc[a][b][3]=0.f; }

    int srow = tid >> 3;                              // 0..31
    int sdst = (tid & 7) << 3;                        // linear dest col (halves)
    int ssrc = (((tid & 7) ^ ((tid >> 3) & 7)) << 3); // pre-swizzled source col

    int fr = lane & 15, fkh = (lane >> 4) << 3;       // fkh in {0,8,16,24} halves
    int ra0 = (fkh)      ^ ((fr & 7) << 3);           // swizzled read offsets
    int ra1 = (fkh + 32) ^ ((fr & 7) << 3);

    for (int k0 = 0; k0 < 1024; k0 += 64) {
        __syncthreads();
        #pragma unroll
        for (int u = 0; u < 4; ++u) {
            GLOAD_LDS(&X[(size_t)(m0+srow+32*u)*1024 + k0 + ssrc], &As[(srow+32*u)*64 + sdst]);
            GLOAD_LDS(&W[(size_t)(n0+srow+32*u)*1024 + k0 + ssrc], &Bs[(srow+32*u)*64 + sdst]);
        }
        __syncthreads();   // compiler drains vmcnt before s_barrier
        f16x8 a0[4], a1[4], b0[4], b1[4];
        #pragma unroll
        for (int a=0;a<4;++a) {
            a0[a] = *(const f16x8*)&As[(wm + a*16 + fr)*64 + ra0];
            a1[a] = *(const f16x8*)&As[(wm + a*16 + fr)*64 + ra1];
        }
        #pragma unroll
        for (int bb=0;bb<4;++bb) {
            b0[bb] = *(const f16x8*)&Bs[(wn + bb*16 + fr)*64 + ra0];
            b1[bb] = *(const f16x8*)&Bs[(wn + bb*16 + fr)*64 + ra1];
        }
        #pragma unroll
        for (int a=0;a<4;++a)
            #pragma unroll
            for (int bb=0;bb<4;++bb) {
                acc[a][bb] = MFMA16(a0[a], b0[bb], acc[a][bb]);
                acc[a][bb] = MFMA16(a1[a], b1[bb], acc[a][bb]);
            }
    }

    int coln = lane & 15, rq = (lane >> 4) << 2;
    #pragma unroll
    for (int tb = 0; tb < 4; ++tb) {
        int j = n0 + wn + tb*16 + coln;
        int hh = j >> 6, dd = j & 63;
        float bsv = bias[j];
        #pragma unroll
        for (int ta = 0; ta < 4; ++ta) {
            #pragma unroll
            for (int r = 0; r < 4; ++r) {
                int m = m0 + wm + ta*16 + rq + r;
                int bidx = m >> 10, s = m & 1023;
                dst[((size_t)(bidx*16 + hh)*1024 + s)*64 + dd] = (f16)(acc[ta][tb][r] + bsv);
            }
        }
    }
}

// ---------------- kernel 3: transpose v -> vT [bh][d][s] ----------------
__global__ __launch_bounds__(256) void transpose_v(f16* __restrict__ ws)
{
    const f16* v = ws + QKV16OFF + 2*4194304 + (size_t)blockIdx.y*65536;
    f16* o       = ws + VTOFF               + (size_t)blockIdx.y*65536;
    int s0 = blockIdx.x << 6;
    __shared__ f16 t[64][72];
    int tid = threadIdx.x;
    int r = tid >> 2, c = (tid & 3) << 4;
    f16x8 a = *(const f16x8*)&v[(size_t)(s0+r)*64 + c];
    f16x8 b = *(const f16x8*)&v[(size_t)(s0+r)*64 + c + 8];
    #pragma unroll
    for (int j = 0; j < 8; ++j) { t[r][c+j] = a[j]; t[r][c+8+j] = b[j]; }
    __syncthreads();
    int dr = tid >> 2, sc0 = (tid & 3) << 4;
    f16x8 o1, o2;
    #pragma unroll
    for (int j = 0; j < 8; ++j) { o1[j] = t[sc0+j][dr]; o2[j] = t[sc0+8+j][dr]; }
    *(f16x8*)&o[(size_t)dr*1024 + s0 + sc0]     = o1;
    *(f16x8*)&o[(size_t)dr*1024 + s0 + sc0 + 8] = o2;
}

// ---------------- kernel 4: fused scores + softmax + attn-write + PV ----------------
// v5 = v2 (round-1, 210us) + three changes:
//  (a) bh-chunked XCD swizzle: consecutive hw block ids (x fastest) round-robin
//      over 8 XCDs; remap so each XCD owns 8 bh processed sequentially ->
//      instantaneous per-XCD read set ~1.3MB, L2-resident.
//  (b) nontemporal attn/out stores (via ext_vector f32x4 — builtin rejects
//      HIP_vector_type): 272MB write stream must not evict K/E/vT from L2.
//  (c) attn-write interleaved into PV loop + setprio around QK MFMA cluster.
__global__ __launch_bounds__(256, 4) void attn_pv(
    const f16* __restrict__ ws, float* __restrict__ attn, float* __restrict__ out)
{
    const f16* qkv = ws + QKV16OFF;
    const f16* er  = ws + ER16OFF;

    // bijective remap: flat = x + 64y; xcd = flat&7 owns bh in [xcd*8, xcd*8+8)
    int flat = blockIdx.x + (blockIdx.y << 6);
    int xcd = flat & 7, j = flat >> 3;
    int bh = (xcd << 3) | (j >> 6);
    int s0 = (j & 63) << 4;
    int h = bh & 15, b = bh >> 4;
    int tid = threadIdx.x, lane = tid & 63, w = tid >> 6;

    const f16* qb  = qkv + (size_t)bh * 65536;
    const f16* kb  = qkv + 4194304 + (size_t)bh * 65536;
    const f16* vtb = ws + VTOFF + (size_t)bh * 65536;
    const f16* E   = er + (size_t)h * 2049 * 64;

    // LDS: P16[w][16][264] f16 (33792 B), overlaid after PV by Ored[w][16][64] f32
    __shared__ __align__(16) f16 lds_pool[4*16*264];
    __shared__ float red[16][4];
    f16* P16 = lds_pool + w * (16*264);

    int fr = lane & 15, fk = (lane >> 4) << 3;
    int hi = lane >> 4;
    f16x8 qf0 = *(const f16x8*)&qb[(s0+fr)*64 + fk];
    f16x8 qf1 = *(const f16x8*)&qb[(s0+fr)*64 + fk + 32];

    int tbase = w << 8;
    int l0 = 1008 + tbase - s0;

    // preload: K tile 0, E tiles l0 and l0+16
    f16x8 kf0 = *(const f16x8*)&kb[(tbase+fr)*64 + fk];
    f16x8 kf1 = *(const f16x8*)&kb[(tbase+fr)*64 + fk + 32];
    f16x8 e0a = *(const f16x8*)&E[(size_t)(l0+fr)*64 + fk];
    f16x8 e0b = *(const f16x8*)&E[(size_t)(l0+fr)*64 + fk + 32];
    f16x8 e1a = *(const f16x8*)&E[(size_t)(l0+16+fr)*64 + fk];
    f16x8 e1b = *(const f16x8*)&E[(size_t)(l0+16+fr)*64 + fk + 32];

    float rs[4] = {0.f, 0.f, 0.f, 0.f};

    #pragma unroll
    for (int i = 0; i < 16; ++i) {
        f16x8 nk0, nk1, nea, neb;
        if (i < 15) {
            int t0n = tbase + ((i+1) << 4);
            nk0 = *(const f16x8*)&kb[(t0n+fr)*64 + fk];
            nk1 = *(const f16x8*)&kb[(t0n+fr)*64 + fk + 32];
            int ln = l0 + ((i+2) << 4);   // max row touched: 2047 < 2049
            nea = *(const f16x8*)&E[(size_t)(ln+fr)*64 + fk];
            neb = *(const f16x8*)&E[(size_t)(ln+fr)*64 + fk + 32];
        }

        __builtin_amdgcn_s_setprio(1);
        f32x4 c = {0.f,0.f,0.f,0.f};
        c = MFMA16(qf0, kf0, c);
        c = MFMA16(qf1, kf1, c);
        f32x4 r0 = {0.f,0.f,0.f,0.f};
        f32x4 r1 = {0.f,0.f,0.f,0.f};
        r0 = MFMA16(qf0, e0a, r0); r0 = MFMA16(qf1, e0b, r0);
        r1 = MFMA16(qf0, e1a, r1); r1 = MFMA16(qf1, e1b, r1);
        __builtin_amdgcn_s_setprio(0);

        #pragma unroll
        for (int r = 0; r < 4; ++r) {
            int shat = (hi << 2) + r;
            int jj = fr - shat + 15;               // [0,30]
            int addr = ((lane & 48) | (jj & 15)) << 2;
            // merged single-bpermute skew gather (disjoint source-lane sets)
            float m = (fr >= 15 - shat) ? r0[r] : r1[r];
            float g = __int_as_float(__builtin_amdgcn_ds_bpermute(addr, __float_as_int(m)));
            float e = __expf((c[r] + g) * 0.125f);  // scores bounded; no max shift
            rs[r] += e;
            P16[shat*264 + (i<<4) + fr] = (f16)e;   // unnormalized exp
        }

        if (i < 15) { kf0 = nk0; kf1 = nk1; e0a = e1a; e0b = e1b; e1a = nea; e1b = neb; }
    }

    // ---- block-wide row-sum reduce ----
    #pragma unroll
    for (int r = 0; r < 4; ++r) {
        float s = rs[r];
        s += __shfl_xor(s, 1); s += __shfl_xor(s, 2);
        s += __shfl_xor(s, 4); s += __shfl_xor(s, 8);
        rs[r] = s;
    }
    if (fr == 0) {
        #pragma unroll
        for (int r = 0; r < 4; ++r) red[(hi<<2)+r][w] = rs[r];
    }
    __syncthreads();   // barrier 1: P16 + red complete, visible block-wide

    // ---- PV with attn-write interleaved (2 write-iters per kc) ----
    float* outb = attn + ((size_t)bh * 1024 + s0) * 1024;
    int arow = tid >> 4;
    int ac0  = (tid & 15) << 2;
    float iv = 1.f / (red[arow][0] + red[arow][1] + red[arow][2] + red[arow][3]);

    f32x4 oacc[4];
    #pragma unroll
    for (int nb=0;nb<4;++nb) { oacc[nb][0]=0.f;oacc[nb][1]=0.f;oacc[nb][2]=0.f;oacc[nb][3]=0.f; }
    f16x8 bcur[4], bnxt[4];
    #pragma unroll
    for (int nb = 0; nb < 4; ++nb)
        bcur[nb] = *(const f16x8*)&vtb[(size_t)((nb<<4)+fr)*1024 + tbase + fk];

    #pragma unroll
    for (int kc = 0; kc < 8; ++kc) {
        // two attn-write iterations (LDS-staged, full-line coalesced, nontemporal)
        #pragma unroll
        for (int u = 0; u < 2; ++u) {
            int it = (kc << 1) + u;
            int col = ac0 + it*64;
            const f16* p = &lds_pool[(col >> 8)*(16*264) + arow*264 + (col & 255)];
            f16x4 p4 = *(const f16x4*)p;
            f32x4 o4;
            o4[0] = (float)p4[0] * iv; o4[1] = (float)p4[1] * iv;
            o4[2] = (float)p4[2] * iv; o4[3] = (float)p4[3] * iv;
            __builtin_nontemporal_store(o4, (f32x4*)&outb[(size_t)arow*1024 + col]);
        }
        if (kc < 7) {
            #pragma unroll
            for (int nb = 0; nb < 4; ++nb)
                bnxt[nb] = *(const f16x8*)&vtb[(size_t)((nb<<4)+fr)*1024 + tbase + ((kc+1)<<5) + fk];
        }
        f16x8 af = *(const f16x8*)&P16[fr*264 + (kc<<5) + fk];
        #pragma unroll
        for (int nb = 0; nb < 4; ++nb)
            oacc[nb] = MFMA16(af, bcur[nb], oacc[nb]);
        if (kc < 7) {
            #pragma unroll
            for (int nb = 0; nb < 4; ++nb) bcur[nb] = bnxt[nb];
        }
    }

    __syncthreads();   // barrier 2: all waves done reading P16 -> overlay Ored
    float* Ored = (float*)lds_pool;
    {
        float iv2[4];
        #pragma unroll
        for (int r = 0; r < 4; ++r) {
            int rw = (hi<<2)+r;
            iv2[r] = 1.f / (red[rw][0] + red[rw][1] + red[rw][2] + red[rw][3]);
        }
        #pragma unroll
        for (int nb = 0; nb < 4; ++nb)
            #pragma unroll
            for (int r = 0; r < 4; ++r) {
                int rw = (hi<<2)+r;
                Ored[w*1024 + rw*64 + (nb<<4) + fr] = oacc[nb][r] * iv2[r];
            }
    }
    __syncthreads();   // barrier 3
    {
        int frow = tid >> 4, fc = (tid & 15) << 2;
        f32x4 s4;
        s4[0] = Ored[frow*64+fc+0] + Ored[1024+frow*64+fc+0] + Ored[2048+frow*64+fc+0] + Ored[3072+frow*64+fc+0];
        s4[1] = Ored[frow*64+fc+1] + Ored[1024+frow*64+fc+1] + Ored[2048+frow*64+fc+1] + Ored[3072+frow*64+fc+1];
        s4[2] = Ored[frow*64+fc+2] + Ored[1024+frow*64+fc+2] + Ored[2048+frow*64+fc+2] + Ored[3072+frow*64+fc+2];
        s4[3] = Ored[frow*64+fc+3] + Ored[1024+frow*64+fc+3] + Ored[2048+frow*64+fc+3] + Ored[3072+frow*64+fc+3];
        __builtin_nontemporal_store(s4,
            (f32x4*)&out[((size_t)b*1024 + s0 + frow)*1024 + h*64 + fc]);
    }
}

extern "C" void kernel_launch(void* const* d_in, const int* in_sizes, int n_in,
                              void* d_out, int out_size, void* d_ws, size_t ws_size,
                              hipStream_t stream) {
    const float* query = (const float*)d_in[0];
    const float* key   = (const float*)d_in[1];
    const float* value = (const float*)d_in[2];
    const float* Wq    = (const float*)d_in[3];
    const float* bq    = (const float*)d_in[4];
    const float* Wk    = (const float*)d_in[5];
    const float* bk    = (const float*)d_in[6];
    const float* Wv    = (const float*)d_in[7];
    const float* bv    = (const float*)d_in[8];

    f16*   ws   = (f16*)d_ws;
    float* out  = (float*)d_out;            // 4,194,304 floats
    float* attn = out + 4194304;            // 67,108,864 floats

    cvt_all    <<<dim3(2048, 1, 7), 256, 0, stream>>>(query, key, value, Wq, Wk, Wv,
                                                      (const float*)d_in[9], ws);
    proj_gemm  <<<dim3(8, 32, 3),   256, 0, stream>>>(ws, bq, bk, bv);
    transpose_v<<<dim3(16, 64),     256, 0, stream>>>(ws);
    attn_pv    <<<dim3(64, 64),     256, 0, stream>>>(ws, attn, out);
}